// Round 7
// baseline (389.471 us; speedup 1.0000x reference)
//
#include <hip/hip_runtime.h>
#include <hip/hip_cooperative_groups.h>
#include <math.h>

namespace cg = cooperative_groups;

namespace {

constexpr int Bn   = 32;
constexpr int Kn   = 32;
constexpr int Fn   = 2048;
constexpr int HIDn = 2;
constexpr int NCLSn = 47;
constexpr float EPSn = 1e-5f;
constexpr int NT = 256;     // threads per block
constexpr int GS = 8;       // split factor along the reduced dim
constexpr int FT = 256;     // LDS tile along the reduced dim (= NT)
constexpr int NB = 512;     // mega-kernel grid (2 blocks/CU co-resident)
constexpr int NTILES = 4 * GS * Bn;  // 1024 logical tiles per heavy phase

typedef float v2f __attribute__((ext_vector_type(2)));

__device__ inline float wave_sum(float v) {
    #pragma unroll
    for (int off = 32; off > 0; off >>= 1) v += __shfl_down(v, off, 64);
    return v;
}

// ---------------------------------------------------------------------------
// Packed inner loop: thread owns adjacent f-pair, accumulates both channels.
__device__ inline void mv_loop(const v2f* __restrict__ xg2, const v2f* __restrict__ yg2,
                               const v2f* __restrict__ t02, const v2f* __restrict__ t12,
                               v2f Xf2, v2f Yf2, v2f& acc0, v2f& acc1) {
    #pragma unroll 8
    for (int j = 0; j < FT; ++j) {
        v2f v = Xf2 * yg2[j] + Yf2 * xg2[j];          // s(f-pair, g)
        v2f S;
        S.x = copysignf(__builtin_amdgcn_sqrtf(fabsf(v.x)), v.x);
        S.y = copysignf(__builtin_amdgcn_sqrtf(fabsf(v.y)), v.y);
        acc0 += S * t02[j];
        acc1 += S * t12[j];
    }
}

// ===========================================================================
// MEGA KERNEL (cooperative): all 7 phases, grid.sync() between.
__global__ __launch_bounds__(NT, 2)
void mega_kernel(const float* __restrict__ x, const float* __restrict__ neighbor,
                 const float* __restrict__ w1, const float* __restrict__ b1,
                 const float* __restrict__ g1, const float* __restrict__ beta1,
                 const float* __restrict__ w2, const float* __restrict__ b2,
                 const float* __restrict__ g2, const float* __restrict__ beta2,
                 const float* __restrict__ Wc, const float* __restrict__ bc,
                 float* __restrict__ out, float* __restrict__ ws) {
    cg::grid_group grid = cg::this_grid();
    const int tid = threadIdx.x;
    const int bid = blockIdx.x;

    float* ysum  = ws;                                   // B*F
    float* dpart = ysum + Bn * Fn;                       // GS*B*F
    float* part  = dpart + (size_t)GS * Bn * Fn;         // GS*B*HID*F
    float* out1  = part + (size_t)GS * Bn * HIDn * Fn;   // B*HID*F
    float* out2  = out1 + Bn * HIDn * Fn;                // B*HID*F
    double* stats = (double*)(out2 + Bn * HIDn * Fn);    // 8 doubles

    __shared__ alignas(16) char smem_raw[16384];
    __shared__ float redsm[4][4];
    v2f* xg2 = (v2f*)smem_raw;       // 256 v2f
    v2f* yg2 = xg2 + FT;
    v2f* t02 = yg2 + FT;
    v2f* t12 = t02 + FT;
    float* zsm = (float*)smem_raw;   // 4096 floats (classifier phase)

    // ---- P0: ysum + zero stats --------------------------------------------
    {
        if (bid == 0 && tid < 8) stats[tid] = 0.0;
        int idx = bid * NT + tid;
        if (idx < Bn * Fn) {
            int b = idx >> 11, g = idx & (Fn - 1);
            const float* p = neighbor + (size_t)b * Kn * Fn + g;
            float s = 0.f;
            #pragma unroll
            for (int k = 0; k < Kn; ++k) s += p[(size_t)k * Fn];
            ysum[idx] = s;
        }
    }
    grid.sync();

    // ---- P1: denom partials -----------------------------------------------
    for (int tile = bid; tile < NTILES; tile += NB) {
        int gtile = tile & 3, fs = (tile >> 2) & 7, b = tile >> 5;
        const float* xb = x + (size_t)b * Fn;
        const float* yb = ysum + (size_t)b * Fn;
        __syncthreads();
        {
            int f = fs * FT + tid;
            float xv = xb[f], yv = yb[f];
            xg2[tid] = (v2f){xv, xv};   // duplicated pairs: (x_f, x_f)
            yg2[tid] = (v2f){yv, yv};
        }
        const int gbase = (gtile * NT + tid) * 2;
        const v2f Xg2 = *(const v2f*)(xb + gbase);
        const v2f Yg2 = *(const v2f*)(yb + gbase);
        __syncthreads();
        v2f dacc = (v2f){0.f, 0.f};
        #pragma unroll 8
        for (int j = 0; j < FT; ++j) {
            v2f v = Xg2 * yg2[j] + Yg2 * xg2[j];
            v2f s2;
            s2.x = __builtin_amdgcn_sqrtf(fabsf(v.x));
            s2.y = __builtin_amdgcn_sqrtf(fabsf(v.y));
            dacc += s2;
        }
        *(v2f*)(dpart + ((size_t)fs * Bn + b) * Fn + gbase) = dacc;
    }
    grid.sync();

    // ---- P2: mv1 partials (inline denom-reduce + t1) ----------------------
    for (int tile = bid; tile < NTILES; tile += NB) {
        int ftile = tile & 3, gs = (tile >> 2) & 7, b = tile >> 5;
        const float* xb = x + (size_t)b * Fn;
        const float* yb = ysum + (size_t)b * Fn;
        __syncthreads();
        {
            int g = gs * FT + tid;
            float d = 0.f;
            #pragma unroll
            for (int fs = 0; fs < GS; ++fs) d += dpart[((size_t)fs * Bn + b) * Fn + g];
            float r = 1.0f / (d + 1e-7f);
            float xg = xb[g], yg = yb[g];
            float t0 = fmaf(w1[0], xg, b1[0]) * r;
            float t1 = fmaf(w1[1], xg, b1[1]) * r;
            xg2[tid] = (v2f){xg, xg};
            yg2[tid] = (v2f){yg, yg};
            t02[tid] = (v2f){t0, t0};
            t12[tid] = (v2f){t1, t1};
        }
        const int fbase = (ftile * NT + tid) * 2;
        const v2f Xf2 = *(const v2f*)(xb + fbase);
        const v2f Yf2 = *(const v2f*)(yb + fbase);
        __syncthreads();
        v2f acc0 = (v2f){0.f, 0.f}, acc1 = (v2f){0.f, 0.f};
        mv_loop(xg2, yg2, t02, t12, Xf2, Yf2, acc0, acc1);
        size_t base = (((size_t)gs * Bn + b) * HIDn) * Fn;
        *(v2f*)(part + base + fbase)      = acc0;
        *(v2f*)(part + base + Fn + fbase) = acc1;
    }
    grid.sync();

    // ---- P3: reduce1 -> out1 + BN1 stats ----------------------------------
    if (bid < (Bn * Fn / 2) / NT) {
        int pidx = bid * NT + tid;
        int b = pidx >> 10, fp = pidx & 1023;
        const size_t stride = (size_t)Bn * HIDn * Fn;
        size_t base = ((size_t)b * HIDn) * Fn + fp * 2;
        v2f o0 = (v2f){0.f, 0.f}, o1 = (v2f){0.f, 0.f};
        #pragma unroll
        for (int gs = 0; gs < GS; ++gs) {
            o0 += *(const v2f*)(part + (size_t)gs * stride + base);
            o1 += *(const v2f*)(part + (size_t)gs * stride + base + Fn);
        }
        *(v2f*)(out1 + base)      = o0;
        *(v2f*)(out1 + base + Fn) = o1;
        float s0 = wave_sum(o0.x + o0.y);
        float s1 = wave_sum(o1.x + o1.y);
        float q0 = wave_sum(o0.x * o0.x + o0.y * o0.y);
        float q1 = wave_sum(o1.x * o1.x + o1.y * o1.y);
        int wid = tid >> 6, lane = tid & 63;
        if (lane == 0) { redsm[wid][0] = s0; redsm[wid][1] = s1; redsm[wid][2] = q0; redsm[wid][3] = q1; }
        __syncthreads();
        if (tid == 0) {
            double S0 = 0, S1 = 0, Q0 = 0, Q1 = 0;
            #pragma unroll
            for (int w = 0; w < 4; ++w) {
                S0 += redsm[w][0]; S1 += redsm[w][1]; Q0 += redsm[w][2]; Q1 += redsm[w][3];
            }
            atomicAdd(&stats[0], S0);
            atomicAdd(&stats[1], S1);
            atomicAdd(&stats[2], Q0);
            atomicAdd(&stats[3], Q1);
        }
    }
    grid.sync();

    // ---- P4: mv2 partials (inline BN1 + softsign + w2 + rden) -------------
    for (int tile = bid; tile < NTILES; tile += NB) {
        int ftile = tile & 3, gs = (tile >> 2) & 7, b = tile >> 5;
        const float* xb = x + (size_t)b * Fn;
        const float* yb = ysum + (size_t)b * Fn;
        __syncthreads();
        {
            const double N = (double)(Bn * Fn);
            double m0d = stats[0] / N, m1d = stats[1] / N;
            float mean0 = (float)m0d, mean1 = (float)m1d;
            float var0 = (float)(stats[2] / N - m0d * m0d);
            float var1 = (float)(stats[3] / N - m1d * m1d);
            float inv0 = rsqrtf(var0 + EPSn) * g1[0];
            float inv1 = rsqrtf(var1 + EPSn) * g1[1];
            int g = gs * FT + tid;
            float d = 0.f;
            #pragma unroll
            for (int fs = 0; fs < GS; ++fs) d += dpart[((size_t)fs * Bn + b) * Fn + g];
            float r = 1.0f / (d + 1e-7f);
            size_t obase = ((size_t)b * HIDn) * Fn + g;
            float o0 = out1[obase], o1 = out1[obase + Fn];
            float y0 = fmaf(o0 - mean0, inv0, beta1[0]);
            float y1 = fmaf(o1 - mean1, inv1, beta1[1]);
            float z0 = y0 / (1.f + fabsf(y0));
            float z1 = y1 / (1.f + fabsf(y1));
            float t0 = fmaf(w2[0], z0, fmaf(w2[1], z1, b2[0])) * r;
            float t1 = fmaf(w2[2], z0, fmaf(w2[3], z1, b2[1])) * r;
            float xg = xb[g], yg = yb[g];
            xg2[tid] = (v2f){xg, xg};
            yg2[tid] = (v2f){yg, yg};
            t02[tid] = (v2f){t0, t0};
            t12[tid] = (v2f){t1, t1};
        }
        const int fbase = (ftile * NT + tid) * 2;
        const v2f Xf2 = *(const v2f*)(xb + fbase);
        const v2f Yf2 = *(const v2f*)(yb + fbase);
        __syncthreads();
        v2f acc0 = (v2f){0.f, 0.f}, acc1 = (v2f){0.f, 0.f};
        mv_loop(xg2, yg2, t02, t12, Xf2, Yf2, acc0, acc1);
        size_t base = (((size_t)gs * Bn + b) * HIDn) * Fn;
        *(v2f*)(part + base + fbase)      = acc0;
        *(v2f*)(part + base + Fn + fbase) = acc1;
    }
    grid.sync();

    // ---- P5: reduce2 -> out2 + BN2 stats ----------------------------------
    if (bid < (Bn * Fn / 2) / NT) {
        int pidx = bid * NT + tid;
        int b = pidx >> 10, fp = pidx & 1023;
        const size_t stride = (size_t)Bn * HIDn * Fn;
        size_t base = ((size_t)b * HIDn) * Fn + fp * 2;
        v2f o0 = (v2f){0.f, 0.f}, o1 = (v2f){0.f, 0.f};
        #pragma unroll
        for (int gs = 0; gs < GS; ++gs) {
            o0 += *(const v2f*)(part + (size_t)gs * stride + base);
            o1 += *(const v2f*)(part + (size_t)gs * stride + base + Fn);
        }
        *(v2f*)(out2 + base)      = o0;
        *(v2f*)(out2 + base + Fn) = o1;
        float s0 = wave_sum(o0.x + o0.y);
        float s1 = wave_sum(o1.x + o1.y);
        float q0 = wave_sum(o0.x * o0.x + o0.y * o0.y);
        float q1 = wave_sum(o1.x * o1.x + o1.y * o1.y);
        int wid = tid >> 6, lane = tid & 63;
        if (lane == 0) { redsm[wid][0] = s0; redsm[wid][1] = s1; redsm[wid][2] = q0; redsm[wid][3] = q1; }
        __syncthreads();
        if (tid == 0) {
            double S0 = 0, S1 = 0, Q0 = 0, Q1 = 0;
            #pragma unroll
            for (int w = 0; w < 4; ++w) {
                S0 += redsm[w][0]; S1 += redsm[w][1]; Q0 += redsm[w][2]; Q1 += redsm[w][3];
            }
            atomicAdd(&stats[4], S0);
            atomicAdd(&stats[5], S1);
            atomicAdd(&stats[6], Q0);
            atomicAdd(&stats[7], Q1);
        }
    }
    grid.sync();

    // ---- P6: BN2 + softsign + classifier ----------------------------------
    {
        const double N = (double)(Bn * Fn);
        double m0d = stats[4] / N, m1d = stats[5] / N;
        float mean0 = (float)m0d, mean1 = (float)m1d;
        float var0 = (float)(stats[6] / N - m0d * m0d);
        float var1 = (float)(stats[7] / N - m1d * m1d);
        float inv0 = rsqrtf(var0 + EPSn) * g2[0];
        float inv1 = rsqrtf(var1 + EPSn) * g2[1];
        float bet0 = beta2[0], bet1 = beta2[1];
        for (int task = bid; task < NCLSn * Bn; task += NB) {
            int n = task % NCLSn;
            int b = task / NCLSn;
            __syncthreads();   // protect zsm reuse across tasks
            const float* src = out2 + (size_t)b * HIDn * Fn;
            #pragma unroll
            for (int it = 0; it < (HIDn * Fn) / NT; ++it) {
                int i = it * NT + tid;
                int c = i >> 11;
                float v = src[i];
                float y = fmaf(v - (c ? mean1 : mean0), (c ? inv1 : inv0), (c ? bet1 : bet0));
                zsm[i] = y / (1.f + fabsf(y));
            }
            __syncthreads();
            const float4* z4 = (const float4*)zsm;
            const float4* w4 = (const float4*)(Wc + (size_t)n * (HIDn * Fn));
            float acc = 0.f;
            #pragma unroll
            for (int it = 0; it < (HIDn * Fn) / (4 * NT); ++it) {
                int i = it * NT + tid;
                float4 a = z4[i];
                float4 w = w4[i];
                acc = fmaf(a.x, w.x, acc);
                acc = fmaf(a.y, w.y, acc);
                acc = fmaf(a.z, w.z, acc);
                acc = fmaf(a.w, w.w, acc);
            }
            float s = wave_sum(acc);
            int wid = tid >> 6, lane = tid & 63;
            if (lane == 0) redsm[wid][0] = s;
            __syncthreads();
            if (tid == 0) {
                float tot = (redsm[0][0] + redsm[1][0]) + (redsm[2][0] + redsm[3][0]);
                out[(size_t)b * NCLSn + n] = tot + bc[n];
            }
        }
    }
}

// ===========================================================================
// FALLBACK PATH: the proven R6 7-kernel chain (used if coop launch fails).
__global__ void ysum_kernel(const float* __restrict__ neighbor,
                            float* __restrict__ ysum,
                            double* __restrict__ stats) {
    int idx = blockIdx.x * NT + threadIdx.x;
    if (blockIdx.x == 0 && threadIdx.x < 8) stats[threadIdx.x] = 0.0;
    int b = idx >> 11;
    int g = idx & (Fn - 1);
    const float* p = neighbor + (size_t)b * Kn * Fn + g;
    float s = 0.f;
    #pragma unroll
    for (int k = 0; k < Kn; ++k) s += p[(size_t)k * Fn];
    ysum[idx] = s;
}

__global__ void denom_partial_kernel(const float* __restrict__ x, const float* __restrict__ ysum,
                                     float* __restrict__ dpart) {
    __shared__ v2f xf2[FT], yf2[FT];
    const int gtile = blockIdx.x;
    const int fs    = blockIdx.y;
    const int b     = blockIdx.z;
    const int tid   = threadIdx.x;
    const float* xb = x + (size_t)b * Fn;
    const float* yb = ysum + (size_t)b * Fn;
    {
        int f = fs * FT + tid;
        float xv = xb[f], yv = yb[f];
        xf2[tid] = (v2f){xv, xv};
        yf2[tid] = (v2f){yv, yv};
    }
    const int gbase = (gtile * NT + tid) * 2;
    const v2f Xg2 = *(const v2f*)(xb + gbase);
    const v2f Yg2 = *(const v2f*)(yb + gbase);
    __syncthreads();
    v2f dacc = (v2f){0.f, 0.f};
    #pragma unroll 8
    for (int j = 0; j < FT; ++j) {
        v2f v = Xg2 * yf2[j] + Yg2 * xf2[j];
        v2f s2;
        s2.x = __builtin_amdgcn_sqrtf(fabsf(v.x));
        s2.y = __builtin_amdgcn_sqrtf(fabsf(v.y));
        dacc += s2;
    }
    size_t base = ((size_t)fs * Bn + b) * Fn;
    *(v2f*)(dpart + base + gbase) = dacc;
}

__global__ void mv1_partial_kernel(const float* __restrict__ x, const float* __restrict__ ysum,
                                   const float* __restrict__ dpart,
                                   const float* __restrict__ w1, const float* __restrict__ b1,
                                   float* __restrict__ part) {
    __shared__ v2f xg2[FT], yg2[FT], t02[FT], t12[FT];
    const int ftile = blockIdx.x;
    const int gs    = blockIdx.y;
    const int b     = blockIdx.z;
    const int tid   = threadIdx.x;
    const float* xb = x + (size_t)b * Fn;
    const float* yb = ysum + (size_t)b * Fn;
    {
        int g = gs * FT + tid;
        float d = 0.f;
        #pragma unroll
        for (int fs = 0; fs < GS; ++fs) d += dpart[((size_t)fs * Bn + b) * Fn + g];
        float r = 1.0f / (d + 1e-7f);
        float xg = xb[g], yg = yb[g];
        float t0 = fmaf(w1[0], xg, b1[0]) * r;
        float t1 = fmaf(w1[1], xg, b1[1]) * r;
        xg2[tid] = (v2f){xg, xg};
        yg2[tid] = (v2f){yg, yg};
        t02[tid] = (v2f){t0, t0};
        t12[tid] = (v2f){t1, t1};
    }
    const int fbase = (ftile * NT + tid) * 2;
    const v2f Xf2 = *(const v2f*)(xb + fbase);
    const v2f Yf2 = *(const v2f*)(yb + fbase);
    __syncthreads();
    v2f acc0 = (v2f){0.f, 0.f}, acc1 = (v2f){0.f, 0.f};
    mv_loop(xg2, yg2, t02, t12, Xf2, Yf2, acc0, acc1);
    size_t base = (((size_t)gs * Bn + b) * HIDn) * Fn;
    *(v2f*)(part + base + fbase)      = acc0;
    *(v2f*)(part + base + Fn + fbase) = acc1;
}

__global__ void mv2_partial_kernel(const float* __restrict__ x, const float* __restrict__ ysum,
                                   const float* __restrict__ dpart, const float* __restrict__ out1,
                                   const double* __restrict__ stats,
                                   const float* __restrict__ g1, const float* __restrict__ beta1,
                                   const float* __restrict__ w2, const float* __restrict__ b2,
                                   float* __restrict__ part) {
    __shared__ v2f xg2[FT], yg2[FT], t02[FT], t12[FT];
    const int ftile = blockIdx.x;
    const int gs    = blockIdx.y;
    const int b     = blockIdx.z;
    const int tid   = threadIdx.x;
    const float* xb = x + (size_t)b * Fn;
    const float* yb = ysum + (size_t)b * Fn;
    {
        const double N = (double)(Bn * Fn);
        double m0d = stats[0] / N, m1d = stats[1] / N;
        float mean0 = (float)m0d, mean1 = (float)m1d;
        float var0 = (float)(stats[2] / N - m0d * m0d);
        float var1 = (float)(stats[3] / N - m1d * m1d);
        float inv0 = rsqrtf(var0 + EPSn) * g1[0];
        float inv1 = rsqrtf(var1 + EPSn) * g1[1];
        int g = gs * FT + tid;
        float d = 0.f;
        #pragma unroll
        for (int fs = 0; fs < GS; ++fs) d += dpart[((size_t)fs * Bn + b) * Fn + g];
        float r = 1.0f / (d + 1e-7f);
        size_t obase = ((size_t)b * HIDn) * Fn + g;
        float o0 = out1[obase], o1 = out1[obase + Fn];
        float y0 = fmaf(o0 - mean0, inv0, beta1[0]);
        float y1 = fmaf(o1 - mean1, inv1, beta1[1]);
        float z0 = y0 / (1.f + fabsf(y0));
        float z1 = y1 / (1.f + fabsf(y1));
        float t0 = fmaf(w2[0], z0, fmaf(w2[1], z1, b2[0])) * r;
        float t1 = fmaf(w2[2], z0, fmaf(w2[3], z1, b2[1])) * r;
        float xg = xb[g], yg = yb[g];
        xg2[tid] = (v2f){xg, xg};
        yg2[tid] = (v2f){yg, yg};
        t02[tid] = (v2f){t0, t0};
        t12[tid] = (v2f){t1, t1};
    }
    const int fbase = (ftile * NT + tid) * 2;
    const v2f Xf2 = *(const v2f*)(xb + fbase);
    const v2f Yf2 = *(const v2f*)(yb + fbase);
    __syncthreads();
    v2f acc0 = (v2f){0.f, 0.f}, acc1 = (v2f){0.f, 0.f};
    mv_loop(xg2, yg2, t02, t12, Xf2, Yf2, acc0, acc1);
    size_t base = (((size_t)gs * Bn + b) * HIDn) * Fn;
    *(v2f*)(part + base + fbase)      = acc0;
    *(v2f*)(part + base + Fn + fbase) = acc1;
}

__global__ void mv_reduce_kernel(const float* __restrict__ part, float* __restrict__ out,
                                 double* __restrict__ stats) {
    __shared__ float red[4][4];
    int pidx = blockIdx.x * NT + threadIdx.x;
    int b = pidx >> 10;
    int fp = pidx & 1023;
    const size_t stride = (size_t)Bn * HIDn * Fn;
    size_t base = ((size_t)b * HIDn) * Fn + fp * 2;
    v2f o0 = (v2f){0.f, 0.f}, o1 = (v2f){0.f, 0.f};
    #pragma unroll
    for (int gs = 0; gs < GS; ++gs) {
        o0 += *(const v2f*)(part + (size_t)gs * stride + base);
        o1 += *(const v2f*)(part + (size_t)gs * stride + base + Fn);
    }
    *(v2f*)(out + base)      = o0;
    *(v2f*)(out + base + Fn) = o1;
    float s0 = wave_sum(o0.x + o0.y);
    float s1 = wave_sum(o1.x + o1.y);
    float q0 = wave_sum(o0.x * o0.x + o0.y * o0.y);
    float q1 = wave_sum(o1.x * o1.x + o1.y * o1.y);
    int wid = threadIdx.x >> 6, lane = threadIdx.x & 63;
    if (lane == 0) { red[wid][0] = s0; red[wid][1] = s1; red[wid][2] = q0; red[wid][3] = q1; }
    __syncthreads();
    if (threadIdx.x == 0) {
        double S0 = 0, S1 = 0, Q0 = 0, Q1 = 0;
        #pragma unroll
        for (int w = 0; w < 4; ++w) {
            S0 += red[w][0]; S1 += red[w][1]; Q0 += red[w][2]; Q1 += red[w][3];
        }
        atomicAdd(&stats[0], S0);
        atomicAdd(&stats[1], S1);
        atomicAdd(&stats[2], Q0);
        atomicAdd(&stats[3], Q1);
    }
}

__global__ void classifier_kernel(const float* __restrict__ out2, const double* __restrict__ stats,
                                  const float* __restrict__ g2, const float* __restrict__ beta2,
                                  const float* __restrict__ Wc, const float* __restrict__ bc,
                                  float* __restrict__ out) {
    __shared__ float z[HIDn * Fn];
    const int n = blockIdx.x;
    const int b = blockIdx.y;
    const double N = (double)(Bn * Fn);
    double m0d = stats[0] / N, m1d = stats[1] / N;
    float mean0 = (float)m0d, mean1 = (float)m1d;
    float var0 = (float)(stats[2] / N - m0d * m0d);
    float var1 = (float)(stats[3] / N - m1d * m1d);
    float inv0 = rsqrtf(var0 + EPSn) * g2[0];
    float inv1 = rsqrtf(var1 + EPSn) * g2[1];
    float bet0 = beta2[0], bet1 = beta2[1];
    const float* src = out2 + (size_t)b * HIDn * Fn;
    #pragma unroll
    for (int it = 0; it < (HIDn * Fn) / NT; ++it) {
        int i = it * NT + threadIdx.x;
        int c = i >> 11;
        float v = src[i];
        float y = fmaf(v - (c ? mean1 : mean0), (c ? inv1 : inv0), (c ? bet1 : bet0));
        z[i] = y / (1.f + fabsf(y));
    }
    __syncthreads();
    const float4* z4 = (const float4*)z;
    const float4* w4 = (const float4*)(Wc + (size_t)n * (HIDn * Fn));
    float acc = 0.f;
    #pragma unroll
    for (int it = 0; it < (HIDn * Fn) / (4 * NT); ++it) {
        int i = it * NT + threadIdx.x;
        float4 a = z4[i];
        float4 w = w4[i];
        acc = fmaf(a.x, w.x, acc);
        acc = fmaf(a.y, w.y, acc);
        acc = fmaf(a.z, w.z, acc);
        acc = fmaf(a.w, w.w, acc);
    }
    __shared__ float red[4];
    float s = wave_sum(acc);
    int wid = threadIdx.x >> 6, lane = threadIdx.x & 63;
    if (lane == 0) red[wid] = s;
    __syncthreads();
    if (threadIdx.x == 0) {
        float tot = (red[0] + red[1]) + (red[2] + red[3]);
        out[(size_t)b * NCLSn + n] = tot + bc[n];
    }
}

} // namespace

extern "C" void kernel_launch(void* const* d_in, const int* in_sizes, int n_in,
                              void* d_out, int out_size, void* d_ws, size_t ws_size,
                              hipStream_t stream) {
    const float* x        = (const float*)d_in[0];
    const float* neighbor = (const float*)d_in[1];
    const float* w1       = (const float*)d_in[2];
    const float* b1       = (const float*)d_in[3];
    const float* g1       = (const float*)d_in[4];
    const float* beta1    = (const float*)d_in[5];
    const float* w2       = (const float*)d_in[6];
    const float* b2       = (const float*)d_in[7];
    const float* g2       = (const float*)d_in[8];
    const float* beta2    = (const float*)d_in[9];
    const float* Wc       = (const float*)d_in[10];
    const float* bc       = (const float*)d_in[11];
    float* out = (float*)d_out;
    float* ws  = (float*)d_ws;

    void* args[] = {(void*)&x, (void*)&neighbor, (void*)&w1, (void*)&b1,
                    (void*)&g1, (void*)&beta1, (void*)&w2, (void*)&b2,
                    (void*)&g2, (void*)&beta2, (void*)&Wc, (void*)&bc,
                    (void*)&out, (void*)&ws};
    hipError_t err = hipLaunchCooperativeKernel((const void*)mega_kernel,
                                                dim3(NB), dim3(NT), args, 0, stream);
    if (err == hipSuccess) return;
    (void)hipGetLastError();  // clear error state; use the proven chain

    float* ysum  = ws;                                   // B*F
    float* dpart = ysum + Bn * Fn;                       // GS*B*F
    float* part  = dpart + (size_t)GS * Bn * Fn;         // GS*B*HID*F
    float* out1  = part + (size_t)GS * Bn * HIDn * Fn;   // B*HID*F
    float* out2  = out1 + Bn * HIDn * Fn;                // B*HID*F
    double* stats = (double*)(out2 + Bn * HIDn * Fn);    // 8 doubles

    const dim3 grid_split(Fn / (NT * 2), GS, Bn);        // (4, 8, 32)

    ysum_kernel<<<(Bn * Fn) / NT, NT, 0, stream>>>(neighbor, ysum, stats);
    denom_partial_kernel<<<grid_split, NT, 0, stream>>>(x, ysum, dpart);
    mv1_partial_kernel<<<grid_split, NT, 0, stream>>>(x, ysum, dpart, w1, b1, part);
    mv_reduce_kernel<<<(Bn * Fn / 2) / NT, NT, 0, stream>>>(part, out1, stats);
    mv2_partial_kernel<<<grid_split, NT, 0, stream>>>(x, ysum, dpart, out1, stats, g1, beta1, w2, b2, part);
    mv_reduce_kernel<<<(Bn * Fn / 2) / NT, NT, 0, stream>>>(part, out2, stats + 4);
    classifier_kernel<<<dim3(NCLSn, Bn), NT, 0, stream>>>(out2, stats + 4, g2, beta2, Wc, bc, out);
}

// Round 8
// 94.564 us; speedup vs baseline: 4.1186x; 4.1186x over previous
//
#include <hip/hip_runtime.h>
#include <math.h>

namespace {

constexpr int Bn   = 32;
constexpr int Kn   = 32;
constexpr int Fn   = 2048;
constexpr int HIDn = 2;
constexpr int NCLSn = 47;
constexpr float EPSn = 1e-5f;
constexpr int NT = 256;     // threads per block
constexpr int GS = 16;      // split factor along the reduced dim
constexpr int FT = Fn / GS; // 128: LDS tile = one slice

typedef float v2f __attribute__((ext_vector_type(2)));
typedef float v4f __attribute__((ext_vector_type(4)));

__device__ inline float wave_sum(float v) {
    #pragma unroll
    for (int off = 32; off > 0; off >>= 1) v += __shfl_down(v, off, 64);
    return v;
}

// ---------------------------------------------------------------------------
// K1: ysum[b,g] = sum_k neighbor[b,k,0,g]; block 0 also zeroes the BN stats.
__global__ void ysum_kernel(const float* __restrict__ neighbor,
                            float* __restrict__ ysum,
                            double* __restrict__ stats) {
    int idx = blockIdx.x * NT + threadIdx.x;          // over B*F
    if (blockIdx.x == 0 && threadIdx.x < 8) stats[threadIdx.x] = 0.0;
    int b = idx >> 11;
    int g = idx & (Fn - 1);
    const float* p = neighbor + (size_t)b * Kn * Fn + g;
    float s = 0.f;
    #pragma unroll
    for (int k = 0; k < Kn; ++k) s += p[(size_t)k * Fn];
    ysum[idx] = s;
}

// ---------------------------------------------------------------------------
// K2: partial denom: dpart[fs][b][g] = sum_{f in slice fs} sqrt(|x_f*y_g + x_g*y_f|)
// grid (Fn/(NT*4), GS, Bn) = (2, 16, 32); each thread owns 4 ADJACENT g.
__global__ __launch_bounds__(NT, 4)
void denom_partial_kernel(const float* __restrict__ x, const float* __restrict__ ysum,
                          float* __restrict__ dpart) {
    __shared__ v2f xf2[FT], yf2[FT];                  // duplicated pairs
    const int gtile = blockIdx.x;
    const int fs    = blockIdx.y;
    const int b     = blockIdx.z;
    const int tid   = threadIdx.x;
    const float* xb = x + (size_t)b * Fn;
    const float* yb = ysum + (size_t)b * Fn;
    if (tid < FT) {
        int f = fs * FT + tid;
        float xv = xb[f], yv = yb[f];
        xf2[tid] = (v2f){xv, xv};
        yf2[tid] = (v2f){yv, yv};
    }
    const int gbase = (gtile * NT + tid) * 4;         // adjacent quad
    const v4f Xg4 = *(const v4f*)(xb + gbase);
    const v4f Yg4 = *(const v4f*)(yb + gbase);
    const v2f Xg01 = (v2f){Xg4.x, Xg4.y}, Xg23 = (v2f){Xg4.z, Xg4.w};
    const v2f Yg01 = (v2f){Yg4.x, Yg4.y}, Yg23 = (v2f){Yg4.z, Yg4.w};
    __syncthreads();
    v2f d01 = (v2f){0.f, 0.f}, d23 = (v2f){0.f, 0.f};
    #pragma unroll 4
    for (int j = 0; j < FT; ++j) {
        v2f xf = xf2[j], yf = yf2[j];
        v2f vA = Xg01 * yf + Yg01 * xf;
        v2f vB = Xg23 * yf + Yg23 * xf;
        v2f sA, sB;
        sA.x = __builtin_amdgcn_sqrtf(fabsf(vA.x));
        sA.y = __builtin_amdgcn_sqrtf(fabsf(vA.y));
        sB.x = __builtin_amdgcn_sqrtf(fabsf(vB.x));
        sB.y = __builtin_amdgcn_sqrtf(fabsf(vB.y));
        d01 += sA;
        d23 += sB;
    }
    v4f dout = (v4f){d01.x, d01.y, d23.x, d23.y};
    *(v4f*)(dpart + ((size_t)fs * Bn + b) * Fn + gbase) = dout;
}

// ---------------------------------------------------------------------------
// Packed inner loop: thread owns 4 adjacent f, accumulates both channels.
__device__ inline void mv_loop4(const v2f* __restrict__ xg2, const v2f* __restrict__ yg2,
                                const v2f* __restrict__ t02, const v2f* __restrict__ t12,
                                v2f Xf01, v2f Xf23, v2f Yf01, v2f Yf23,
                                v2f& a00, v2f& a10, v2f& a01, v2f& a11) {
    #pragma unroll 4
    for (int j = 0; j < FT; ++j) {
        v2f xg = xg2[j], yg = yg2[j];
        v2f vA = Xf01 * yg + Yf01 * xg;               // s(f01, g)
        v2f vB = Xf23 * yg + Yf23 * xg;               // s(f23, g)
        v2f SA, SB;
        SA.x = copysignf(__builtin_amdgcn_sqrtf(fabsf(vA.x)), vA.x);
        SA.y = copysignf(__builtin_amdgcn_sqrtf(fabsf(vA.y)), vA.y);
        SB.x = copysignf(__builtin_amdgcn_sqrtf(fabsf(vB.x)), vB.x);
        SB.y = copysignf(__builtin_amdgcn_sqrtf(fabsf(vB.y)), vB.y);
        v2f t0 = t02[j], t1 = t12[j];
        a00 += SA * t0;
        a10 += SA * t1;
        a01 += SB * t0;
        a11 += SB * t1;
    }
}

// K3: pass-1 partial matvec with inline denom-reduce + t1 = (w1*x+b1)*rden.
// grid (2, GS, Bn); each thread owns 4 adjacent f, both channels.
__global__ __launch_bounds__(NT, 4)
void mv1_partial_kernel(const float* __restrict__ x, const float* __restrict__ ysum,
                        const float* __restrict__ dpart,
                        const float* __restrict__ w1, const float* __restrict__ b1,
                        float* __restrict__ part) {
    __shared__ v2f xg2[FT], yg2[FT], t02[FT], t12[FT];
    const int ftile = blockIdx.x;
    const int gs    = blockIdx.y;
    const int b     = blockIdx.z;
    const int tid   = threadIdx.x;
    const float* xb = x + (size_t)b * Fn;
    const float* yb = ysum + (size_t)b * Fn;
    if (tid < FT) {
        int g = gs * FT + tid;
        float d = 0.f;
        #pragma unroll
        for (int fs = 0; fs < GS; ++fs) d += dpart[((size_t)fs * Bn + b) * Fn + g];
        float r = 1.0f / (d + 1e-7f);
        float xg = xb[g], yg = yb[g];
        float t0 = fmaf(w1[0], xg, b1[0]) * r;
        float t1 = fmaf(w1[1], xg, b1[1]) * r;
        xg2[tid] = (v2f){xg, xg};
        yg2[tid] = (v2f){yg, yg};
        t02[tid] = (v2f){t0, t0};
        t12[tid] = (v2f){t1, t1};
    }
    const int fbase = (ftile * NT + tid) * 4;
    const v4f X4 = *(const v4f*)(xb + fbase);
    const v4f Y4 = *(const v4f*)(yb + fbase);
    __syncthreads();
    v2f a00 = (v2f){0.f, 0.f}, a10 = a00, a01 = a00, a11 = a00;
    mv_loop4(xg2, yg2, t02, t12,
             (v2f){X4.x, X4.y}, (v2f){X4.z, X4.w},
             (v2f){Y4.x, Y4.y}, (v2f){Y4.z, Y4.w}, a00, a10, a01, a11);
    size_t base = (((size_t)gs * Bn + b) * HIDn) * Fn;
    *(v4f*)(part + base + fbase)      = (v4f){a00.x, a00.y, a01.x, a01.y};
    *(v4f*)(part + base + Fn + fbase) = (v4f){a10.x, a10.y, a11.x, a11.y};
}

// K5: pass-2 partial matvec with inline BN1 + softsign + w2 + rden recompute.
__global__ __launch_bounds__(NT, 4)
void mv2_partial_kernel(const float* __restrict__ x, const float* __restrict__ ysum,
                        const float* __restrict__ dpart, const float* __restrict__ out1,
                        const double* __restrict__ stats,
                        const float* __restrict__ g1, const float* __restrict__ beta1,
                        const float* __restrict__ w2, const float* __restrict__ b2,
                        float* __restrict__ part) {
    __shared__ v2f xg2[FT], yg2[FT], t02[FT], t12[FT];
    const int ftile = blockIdx.x;
    const int gs    = blockIdx.y;
    const int b     = blockIdx.z;
    const int tid   = threadIdx.x;
    const float* xb = x + (size_t)b * Fn;
    const float* yb = ysum + (size_t)b * Fn;
    if (tid < FT) {
        const double N = (double)(Bn * Fn);
        double m0d = stats[0] / N, m1d = stats[1] / N;
        float mean0 = (float)m0d, mean1 = (float)m1d;
        float var0 = (float)(stats[2] / N - m0d * m0d);
        float var1 = (float)(stats[3] / N - m1d * m1d);
        float inv0 = rsqrtf(var0 + EPSn) * g1[0];
        float inv1 = rsqrtf(var1 + EPSn) * g1[1];
        int g = gs * FT + tid;
        float d = 0.f;
        #pragma unroll
        for (int fs = 0; fs < GS; ++fs) d += dpart[((size_t)fs * Bn + b) * Fn + g];
        float r = 1.0f / (d + 1e-7f);
        size_t obase = ((size_t)b * HIDn) * Fn + g;
        float o0 = out1[obase], o1 = out1[obase + Fn];
        float y0 = fmaf(o0 - mean0, inv0, beta1[0]);
        float y1 = fmaf(o1 - mean1, inv1, beta1[1]);
        float z0 = y0 / (1.f + fabsf(y0));
        float z1 = y1 / (1.f + fabsf(y1));
        float t0 = fmaf(w2[0], z0, fmaf(w2[1], z1, b2[0])) * r;
        float t1 = fmaf(w2[2], z0, fmaf(w2[3], z1, b2[1])) * r;
        float xg = xb[g], yg = yb[g];
        xg2[tid] = (v2f){xg, xg};
        yg2[tid] = (v2f){yg, yg};
        t02[tid] = (v2f){t0, t0};
        t12[tid] = (v2f){t1, t1};
    }
    const int fbase = (ftile * NT + tid) * 4;
    const v4f X4 = *(const v4f*)(xb + fbase);
    const v4f Y4 = *(const v4f*)(yb + fbase);
    __syncthreads();
    v2f a00 = (v2f){0.f, 0.f}, a10 = a00, a01 = a00, a11 = a00;
    mv_loop4(xg2, yg2, t02, t12,
             (v2f){X4.x, X4.y}, (v2f){X4.z, X4.w},
             (v2f){Y4.x, Y4.y}, (v2f){Y4.z, Y4.w}, a00, a10, a01, a11);
    size_t base = (((size_t)gs * Bn + b) * HIDn) * Fn;
    *(v4f*)(part + base + fbase)      = (v4f){a00.x, a00.y, a01.x, a01.y};
    *(v4f*)(part + base + Fn + fbase) = (v4f){a10.x, a10.y, a11.x, a11.y};
}

// ---------------------------------------------------------------------------
// K4/K6: reduce matvec partials -> out[b,c,f], plus BN statistics.
// grid ((B*F/4)/NT = 64, NT); each thread reduces one adjacent f-quad, both ch.
__global__ void mv_reduce_kernel(const float* __restrict__ part, float* __restrict__ out,
                                 double* __restrict__ stats) {
    __shared__ float red[4][4];
    int pidx = blockIdx.x * NT + threadIdx.x;         // over B*F/4 quads
    int b = pidx >> 9;                                // 512 quads per b
    int fq = pidx & 511;
    const size_t stride = (size_t)Bn * HIDn * Fn;
    size_t base = ((size_t)b * HIDn) * Fn + fq * 4;
    v4f o0 = (v4f){0.f, 0.f, 0.f, 0.f}, o1 = o0;
    #pragma unroll
    for (int gs = 0; gs < GS; ++gs) {
        o0 += *(const v4f*)(part + (size_t)gs * stride + base);
        o1 += *(const v4f*)(part + (size_t)gs * stride + base + Fn);
    }
    *(v4f*)(out + base)      = o0;
    *(v4f*)(out + base + Fn) = o1;
    float s0 = wave_sum((o0.x + o0.y) + (o0.z + o0.w));
    float s1 = wave_sum((o1.x + o1.y) + (o1.z + o1.w));
    float q0 = wave_sum((o0.x * o0.x + o0.y * o0.y) + (o0.z * o0.z + o0.w * o0.w));
    float q1 = wave_sum((o1.x * o1.x + o1.y * o1.y) + (o1.z * o1.z + o1.w * o1.w));
    int wid = threadIdx.x >> 6, lane = threadIdx.x & 63;
    if (lane == 0) { red[wid][0] = s0; red[wid][1] = s1; red[wid][2] = q0; red[wid][3] = q1; }
    __syncthreads();
    if (threadIdx.x == 0) {
        double S0 = 0, S1 = 0, Q0 = 0, Q1 = 0;
        #pragma unroll
        for (int w = 0; w < 4; ++w) {
            S0 += red[w][0]; S1 += red[w][1]; Q0 += red[w][2]; Q1 += red[w][3];
        }
        atomicAdd(&stats[0], S0);
        atomicAdd(&stats[1], S1);
        atomicAdd(&stats[2], Q0);
        atomicAdd(&stats[3], Q1);
    }
}

// ---------------------------------------------------------------------------
// K7: fused BN2 + softsign (into LDS) + classifier. grid (NCLS, B).
__global__ void classifier_kernel(const float* __restrict__ out2, const double* __restrict__ stats,
                                  const float* __restrict__ g2, const float* __restrict__ beta2,
                                  const float* __restrict__ Wc, const float* __restrict__ bc,
                                  float* __restrict__ out) {
    __shared__ float z[HIDn * Fn];  // 16 KiB
    const int n = blockIdx.x;
    const int b = blockIdx.y;
    const double N = (double)(Bn * Fn);
    double m0d = stats[0] / N, m1d = stats[1] / N;
    float mean0 = (float)m0d, mean1 = (float)m1d;
    float var0 = (float)(stats[2] / N - m0d * m0d);
    float var1 = (float)(stats[3] / N - m1d * m1d);
    float inv0 = rsqrtf(var0 + EPSn) * g2[0];
    float inv1 = rsqrtf(var1 + EPSn) * g2[1];
    float bet0 = beta2[0], bet1 = beta2[1];
    const float* src = out2 + (size_t)b * HIDn * Fn;
    #pragma unroll
    for (int it = 0; it < (HIDn * Fn) / NT; ++it) {
        int i = it * NT + threadIdx.x;
        int c = i >> 11;
        float v = src[i];
        float y = fmaf(v - (c ? mean1 : mean0), (c ? inv1 : inv0), (c ? bet1 : bet0));
        z[i] = y / (1.f + fabsf(y));
    }
    __syncthreads();
    const float4* z4 = (const float4*)z;
    const float4* w4 = (const float4*)(Wc + (size_t)n * (HIDn * Fn));
    float acc = 0.f;
    #pragma unroll
    for (int it = 0; it < (HIDn * Fn) / (4 * NT); ++it) {
        int i = it * NT + threadIdx.x;
        float4 a = z4[i];
        float4 w = w4[i];
        acc = fmaf(a.x, w.x, acc);
        acc = fmaf(a.y, w.y, acc);
        acc = fmaf(a.z, w.z, acc);
        acc = fmaf(a.w, w.w, acc);
    }
    __shared__ float red[4];
    float s = wave_sum(acc);
    int wid = threadIdx.x >> 6, lane = threadIdx.x & 63;
    if (lane == 0) red[wid] = s;
    __syncthreads();
    if (threadIdx.x == 0) {
        float tot = (red[0] + red[1]) + (red[2] + red[3]);
        out[(size_t)b * NCLSn + n] = tot + bc[n];
    }
}

} // namespace

extern "C" void kernel_launch(void* const* d_in, const int* in_sizes, int n_in,
                              void* d_out, int out_size, void* d_ws, size_t ws_size,
                              hipStream_t stream) {
    const float* x        = (const float*)d_in[0];
    const float* neighbor = (const float*)d_in[1];
    const float* w1       = (const float*)d_in[2];
    const float* b1       = (const float*)d_in[3];
    const float* g1       = (const float*)d_in[4];
    const float* beta1    = (const float*)d_in[5];
    const float* w2       = (const float*)d_in[6];
    const float* b2       = (const float*)d_in[7];
    const float* g2       = (const float*)d_in[8];
    const float* beta2    = (const float*)d_in[9];
    const float* Wc       = (const float*)d_in[10];
    const float* bc       = (const float*)d_in[11];
    float* out = (float*)d_out;

    float* ws    = (float*)d_ws;
    float* ysum  = ws;                                  // B*F
    float* dpart = ysum + Bn * Fn;                      // GS*B*F
    float* part  = dpart + (size_t)GS * Bn * Fn;        // GS*B*HID*F
    float* out1  = part + (size_t)GS * Bn * HIDn * Fn;  // B*HID*F
    float* out2  = out1 + Bn * HIDn * Fn;               // B*HID*F
    double* stats = (double*)(out2 + Bn * HIDn * Fn);   // 8 doubles

    const dim3 grid_split(Fn / (NT * 4), GS, Bn);       // (2, 16, 32) = 1024 blocks

    ysum_kernel<<<(Bn * Fn) / NT, NT, 0, stream>>>(neighbor, ysum, stats);
    denom_partial_kernel<<<grid_split, NT, 0, stream>>>(x, ysum, dpart);
    mv1_partial_kernel<<<grid_split, NT, 0, stream>>>(x, ysum, dpart, w1, b1, part);
    mv_reduce_kernel<<<(Bn * Fn / 4) / NT, NT, 0, stream>>>(part, out1, stats);
    mv2_partial_kernel<<<grid_split, NT, 0, stream>>>(x, ysum, dpart, out1, stats, g1, beta1, w2, b2, part);
    mv_reduce_kernel<<<(Bn * Fn / 4) / NT, NT, 0, stream>>>(part, out2, stats + 4);
    classifier_kernel<<<dim3(NCLSn, Bn), NT, 0, stream>>>(out2, stats + 4, g2, beta2, Wc, bc, out);
}